// Round 2
// baseline (262.361 us; speedup 1.0000x reference)
//
#include <hip/hip_runtime.h>
#include <hip/hip_cooperative_groups.h>

namespace cg = cooperative_groups;

// ---- types ----
typedef _Float16 halfx8 __attribute__((ext_vector_type(8)));
typedef float floatx4 __attribute__((ext_vector_type(4)));

#define GLOBAL_AS __attribute__((address_space(1)))
#define LDS_AS __attribute__((address_space(3)))

// async global->LDS, 16B per lane; LDS dest = wave-uniform base + lane*16
__device__ __forceinline__ void async_copy_16(const void* g, void* l) {
    __builtin_amdgcn_global_load_lds((GLOBAL_AS void*)g, (LDS_AS void*)l, 16, 0, 0);
}

// problem dims
#define PM 16384
#define PD 768
#define PA 51

// Math identity (verified R5 of prior session):
//   logits = x @ (Wa@We)^T + (Wa@b_embed + b_attr).   h is never materialized.

// ================= prep: W_comb + b_comb + stats zero =================
// Separate launch so wc32/bc cross a kernel boundary (runtime-guaranteed
// coherence) instead of relying on intra-kernel cross-XCD fences.
// 95 blocks x 4 waves = 380 waves; 377 used.
__global__ __launch_bounds__(256) void prep_kernel(
    const float* __restrict__ We, const float* __restrict__ be,
    const float* __restrict__ Wa, const float* __restrict__ ba,
    float* __restrict__ wc32, float* __restrict__ bc, float* __restrict__ stats)
{
    const int wave = threadIdx.x >> 6;
    const int lane = threadIdx.x & 63;
    const int Wu = __builtin_amdgcn_readfirstlane((int)blockIdx.x * 4 + wave);

    if (Wu < 312) {
        // wc[a][d] = sum_k Wa[a][k] * We[k][d]; 2 attrs x 64 cols per wave.
        // 26 attr-pairs x 12 col-chunks = 312 waves.
        const int pair = Wu / 12;
        const int dchunk = Wu - pair * 12;
        const int a0 = pair * 2;
        const bool has1 = (a0 + 1 < PA);
        const int d = dchunk * 64 + lane;
        const float* wa0 = Wa + (size_t)a0 * PD;                 // wave-uniform -> s_load
        const float* wa1 = Wa + (size_t)(has1 ? a0 + 1 : a0) * PD;
        float acc0 = 0.f, acc1 = 0.f;
        #pragma unroll 32
        for (int k = 0; k < PD; ++k) {
            float w = We[(size_t)k * PD + d];   // coalesced 256B/wave, L2-resident
            acc0 = fmaf(w, wa0[k], acc0);
            acc1 = fmaf(w, wa1[k], acc1);
        }
        wc32[(size_t)a0 * PD + d] = acc0;
        if (has1) wc32[(size_t)(a0 + 1) * PD + d] = acc1;
    } else if (Wu < 325) {
        // zero pad rows 51..63 so B-staging reads defined data
        const int r = PA + (Wu - 312);
        #pragma unroll
        for (int j = 0; j < 12; ++j)
            wc32[(size_t)r * PD + j * 64 + lane] = 0.f;
    } else if (Wu < 376) {
        // bc[a] = dot(Wa[a], b_embed) + b_attr[a]; one wave per attr
        const int a = Wu - 325;
        float p = 0.f;
        #pragma unroll
        for (int j = 0; j < 12; ++j) {
            int k = j * 64 + lane;
            p = fmaf(Wa[(size_t)a * PD + k], be[k], p);
        }
        #pragma unroll
        for (int off = 32; off; off >>= 1) p += __shfl_down(p, off);
        if (lane == 0) bc[a] = p + ba[a];
    } else if (Wu == 376) {
        stats[lane] = 0.f;
        stats[64 + lane] = 0.f;
    }
}

// ================= fused GEMM + BN (cooperative) =================
// 512 blocks x 256 threads (2/CU). Phase A: skinny MFMA GEMM, logits stay in
// registers, per-attr sum/sumsq -> device-scope atomics. grid.sync. Phase B:
// BN normalize from registers, write out directly (no logits round-trip).
__global__ void __launch_bounds__(256, 2) gemm_bn_kernel(
    const float* __restrict__ X,        // [16384][768] fp32
    const float* __restrict__ Wc,       // [64][768] fp32, rows >= 51 zero
    const float* __restrict__ bc,       // [64]
    const float* __restrict__ gamma,
    const float* __restrict__ beta,
    float* __restrict__ out,            // [16384][51]
    float* __restrict__ stats)          // [0..50]=sum, [64..114]=sumsq
{
    __shared__ float As[2][32 * 64];   // 2 x 8 KB
    __shared__ float Bs[2][64 * 64];   // 2 x 16 KB
    __shared__ float s_sum[64];
    __shared__ float s_ssq[64];

    const int tid = threadIdx.x;
    const int wave = tid >> 6;
    const int lane = tid & 63;
    const int quad = lane >> 4;
    const int l16 = lane & 15;
    const int wr = wave & 1;            // row half
    const int wn = wave >> 1;           // attr half
    const int row0 = (int)blockIdx.x * 32;
    const int g_r  = lane >> 4;         // 4 rows per 1KB async group
    const int g_sl = lane & 15;         // dest chunk slot 0..15

    if (tid < 64) { s_sum[tid] = 0.f; s_ssq[tid] = 0.f; }

    floatx4 acc[2];
    acc[0] = (floatx4){0.f, 0.f, 0.f, 0.f};
    acc[1] = (floatx4){0.f, 0.f, 0.f, 0.f};

    // stage one 64-K tile (A: 32 rows, B: 64 rows); 6 asyncs per thread
    auto stage = [&](float* AsB, float* BsB, int kt) {
        #pragma unroll
        for (int j = 0; j < 2; ++j) {
            int g = wave * 2 + j;            // 0..7
            int r = g * 4 + g_r;             // 0..31
            int csrc = g_sl ^ (r & 7);
            async_copy_16(X + (size_t)(row0 + r) * PD + kt + csrc * 4, AsB + g * 256);
        }
        #pragma unroll
        for (int j = 0; j < 4; ++j) {
            int g = wave * 4 + j;            // 0..15
            int r = g * 4 + g_r;             // 0..63
            int csrc = g_sl ^ (r & 7);
            async_copy_16(Wc + (size_t)r * PD + kt + csrc * 4, BsB + g * 256);
        }
    };

    auto compute = [&](const float* AsB, const float* BsB) {
        #pragma unroll
        for (int ks = 0; ks < 2; ++ks) {
            int c0 = ks * 8 + quad * 2;      // first 4-float chunk of my k-octet
            int sw = l16 & 7;
            int rA = wr * 16 + l16;
            floatx4 p0 = *(const floatx4*)&AsB[rA * 64 + ((c0 ^ sw) << 2)];
            floatx4 p1 = *(const floatx4*)&AsB[rA * 64 + (((c0 + 1) ^ sw) << 2)];
            halfx8 af;
            af[0] = (_Float16)p0[0]; af[1] = (_Float16)p0[1];
            af[2] = (_Float16)p0[2]; af[3] = (_Float16)p0[3];
            af[4] = (_Float16)p1[0]; af[5] = (_Float16)p1[1];
            af[6] = (_Float16)p1[2]; af[7] = (_Float16)p1[3];
            #pragma unroll
            for (int ni = 0; ni < 2; ++ni) {
                int rB = wn * 32 + ni * 16 + l16;
                floatx4 q0 = *(const floatx4*)&BsB[rB * 64 + ((c0 ^ sw) << 2)];
                floatx4 q1 = *(const floatx4*)&BsB[rB * 64 + (((c0 + 1) ^ sw) << 2)];
                halfx8 bf;
                bf[0] = (_Float16)q0[0]; bf[1] = (_Float16)q0[1];
                bf[2] = (_Float16)q0[2]; bf[3] = (_Float16)q0[3];
                bf[4] = (_Float16)q1[0]; bf[5] = (_Float16)q1[1];
                bf[6] = (_Float16)q1[2]; bf[7] = (_Float16)q1[3];
                acc[ni] = __builtin_amdgcn_mfma_f32_16x16x32_f16(af, bf, acc[ni], 0, 0, 0);
            }
        }
    };

    // Counted-vmcnt double-buffer pipeline (T3/T4 minimum form).
    //   barrier-1: vmcnt(6) -> tile t's 6 own-wave loads retired; barrier makes
    //              it grid... block-wide. Tile t+1's 6 loads stay in flight.
    //   barrier-2: lgkmcnt(0) -> every wave's ds_reads of buffer cur fully
    //              drained BEFORE any wave can start overwriting it (R1 bug fix).
    stage(As[0], Bs[0], 0);
    #pragma unroll
    for (int t = 0; t < 12; ++t) {
        const int cur = t & 1;
        if (t < 11) {
            stage(As[cur ^ 1], Bs[cur ^ 1], (t + 1) * 64);
            asm volatile("s_waitcnt vmcnt(6)\n\ts_barrier" ::: "memory");
        } else {
            asm volatile("s_waitcnt vmcnt(0)\n\ts_barrier" ::: "memory");
        }
        compute(As[cur], Bs[cur]);
        asm volatile("s_waitcnt lgkmcnt(0)\n\ts_barrier" ::: "memory");
    }

    // epilogue: D col (n) = attr, D row (m) = quad*4 + r (m89-verified layout)
    float keep[2][4];
    int cols[2];
    #pragma unroll
    for (int ni = 0; ni < 2; ++ni) {
        int col = wn * 32 + ni * 16 + l16;
        cols[ni] = col;
        if (col < PA) {
            float bv = bc[col];
            float ps = 0.f, pss = 0.f;
            #pragma unroll
            for (int r = 0; r < 4; ++r) {
                float v = acc[ni][r] + bv;
                keep[ni][r] = v;
                ps += v; pss += v * v;
            }
            atomicAdd(&s_sum[col], ps);
            atomicAdd(&s_ssq[col], pss);
        }
    }
    __syncthreads();
    if (tid < PA) {
        atomicAdd(&stats[tid], s_sum[tid]);        // device-scope (coherent)
        atomicAdd(&stats[64 + tid], s_ssq[tid]);
    }

    __threadfence();
    cg::this_grid().sync();

    // ================= BN finalize from registers =================
    const float invB = 1.0f / (float)PM;
    #pragma unroll
    for (int ni = 0; ni < 2; ++ni) {
        int col = cols[ni];
        if (col < PA) {
            float s  = __hip_atomic_load(&stats[col],      __ATOMIC_RELAXED, __HIP_MEMORY_SCOPE_AGENT);
            float ss = __hip_atomic_load(&stats[64 + col], __ATOMIC_RELAXED, __HIP_MEMORY_SCOPE_AGENT);
            float mean = s * invB;
            float var  = ss * invB - mean * mean;
            float inv  = rsqrtf(var + 1e-5f);
            float scale = gamma[col] * inv;
            float shift = beta[col] - mean * scale;
            int rowb = row0 + wr * 16 + quad * 4;
            #pragma unroll
            for (int r = 0; r < 4; ++r)
                out[(size_t)(rowb + r) * PA + col] = keep[ni][r] * scale + shift;
        }
    }
}

// ------------------- launch -------------------
extern "C" void kernel_launch(void* const* d_in, const int* in_sizes, int n_in,
                              void* d_out, int out_size, void* d_ws, size_t ws_size,
                              hipStream_t stream) {
    const float* x       = (const float*)d_in[0];
    const float* W_embed = (const float*)d_in[1];
    const float* b_embed = (const float*)d_in[2];
    const float* W_attr  = (const float*)d_in[3];
    const float* b_attr  = (const float*)d_in[4];
    const float* gamma   = (const float*)d_in[5];
    const float* beta    = (const float*)d_in[6];
    float* out = (float*)d_out;

    char* ws = (char*)d_ws;
    float* wc32  = (float*)(ws);                  // 64*768*4 = 196608
    float* bc    = (float*)(ws + 196608);         // 64*4     = 256
    float* stats = (float*)(ws + 196864);         // 128*4    = 512

    prep_kernel<<<95, 256, 0, stream>>>(W_embed, b_embed, W_attr, b_attr, wc32, bc, stats);

    void* args[] = {
        (void*)&x, (void*)&wc32, (void*)&bc,
        (void*)&gamma, (void*)&beta, (void*)&out, (void*)&stats
    };
    hipLaunchCooperativeKernel(reinterpret_cast<void*>(gemm_bn_kernel),
                               dim3(512), dim3(256), args, 0, stream);
}

// Round 3
// 187.106 us; speedup vs baseline: 1.4022x; 1.4022x over previous
//
#include <hip/hip_runtime.h>

// ---- types ----
typedef _Float16 halfx8 __attribute__((ext_vector_type(8)));
typedef float floatx4 __attribute__((ext_vector_type(4)));

#define GLOBAL_AS __attribute__((address_space(1)))
#define LDS_AS __attribute__((address_space(3)))

// async global->LDS, 16B per lane; LDS dest = wave-uniform base + lane*16
__device__ __forceinline__ void async_copy_16(const void* g, void* l) {
    __builtin_amdgcn_global_load_lds((GLOBAL_AS void*)g, (LDS_AS void*)l, 16, 0, 0);
}

// problem dims
#define PM 16384
#define PD 768
#define PA 51
#define NBLK 512u

// Math identity (verified): logits = x @ (Wa@We)^T + (Wa@b_embed + b_attr).

// ================= prep: W_comb + b_comb + stats/counter zero =================
// Separate launch so wc32/bc cross a kernel boundary (runtime-guaranteed
// coherence). 95 blocks x 4 waves = 380 waves; 377 used.
__global__ __launch_bounds__(256) void prep_kernel(
    const float* __restrict__ We, const float* __restrict__ be,
    const float* __restrict__ Wa, const float* __restrict__ ba,
    float* __restrict__ wc32, float* __restrict__ bc, float* __restrict__ stats,
    unsigned int* __restrict__ counter)
{
    const int wave = threadIdx.x >> 6;
    const int lane = threadIdx.x & 63;
    const int Wu = __builtin_amdgcn_readfirstlane((int)blockIdx.x * 4 + wave);

    if (Wu < 312) {
        // wc[a][d] = sum_k Wa[a][k] * We[k][d]; 2 attrs x 64 cols per wave.
        const int pair = Wu / 12;
        const int dchunk = Wu - pair * 12;
        const int a0 = pair * 2;
        const bool has1 = (a0 + 1 < PA);
        const int d = dchunk * 64 + lane;
        const float* wa0 = Wa + (size_t)a0 * PD;                 // wave-uniform -> s_load
        const float* wa1 = Wa + (size_t)(has1 ? a0 + 1 : a0) * PD;
        float acc0 = 0.f, acc1 = 0.f;
        #pragma unroll 32
        for (int k = 0; k < PD; ++k) {
            float w = We[(size_t)k * PD + d];   // coalesced 256B/wave
            acc0 = fmaf(w, wa0[k], acc0);
            acc1 = fmaf(w, wa1[k], acc1);
        }
        wc32[(size_t)a0 * PD + d] = acc0;
        if (has1) wc32[(size_t)(a0 + 1) * PD + d] = acc1;
    } else if (Wu < 325) {
        // zero pad rows 51..63 so B-staging reads defined data
        const int r = PA + (Wu - 312);
        #pragma unroll
        for (int j = 0; j < 12; ++j)
            wc32[(size_t)r * PD + j * 64 + lane] = 0.f;
    } else if (Wu < 376) {
        // bc[a] = dot(Wa[a], b_embed) + b_attr[a]; one wave per attr
        const int a = Wu - 325;
        float p = 0.f;
        #pragma unroll
        for (int j = 0; j < 12; ++j) {
            int k = j * 64 + lane;
            p = fmaf(Wa[(size_t)a * PD + k], be[k], p);
        }
        #pragma unroll
        for (int off = 32; off; off >>= 1) p += __shfl_down(p, off);
        if (lane == 0) bc[a] = p + ba[a];
    } else if (Wu == 376) {
        stats[lane] = 0.f;
        stats[64 + lane] = 0.f;
        if (lane == 0) *counter = 0u;            // reset spin barrier each replay
    }
}

// ================= fused GEMM + BN (regular launch, spin barrier) =================
// 512 blocks x 256 threads == exactly 2 blocks/CU x 256 CUs, guaranteed
// co-resident by __launch_bounds__(256,2) (LDS 48.5KB -> 3 blocks/CU cap).
// Phase A: skinny MFMA GEMM, logits stay in registers, per-attr sum/sumsq ->
// device-scope atomics. Spin barrier on device-atomic counter (no threadfence,
// no cooperative launch). Phase B: BN normalize from registers, write out.
__global__ void __launch_bounds__(256, 2) gemm_bn_kernel(
    const float* __restrict__ X,        // [16384][768] fp32
    const float* __restrict__ Wc,       // [64][768] fp32, rows >= 51 zero
    const float* __restrict__ bc,       // [64]
    const float* __restrict__ gamma,
    const float* __restrict__ beta,
    float* __restrict__ out,            // [16384][51]
    float* __restrict__ stats,          // [0..50]=sum, [64..114]=sumsq
    unsigned int* __restrict__ counter)
{
    __shared__ float As[2][32 * 64];   // 2 x 8 KB
    __shared__ float Bs[2][64 * 64];   // 2 x 16 KB
    __shared__ float s_sum[64];
    __shared__ float s_ssq[64];

    const int tid = threadIdx.x;
    const int wave = tid >> 6;
    const int lane = tid & 63;
    const int quad = lane >> 4;
    const int l16 = lane & 15;
    const int wr = wave & 1;            // row half
    const int wn = wave >> 1;           // attr half
    const int row0 = (int)blockIdx.x * 32;
    const int g_r  = lane >> 4;         // 4 rows per 1KB async group
    const int g_sl = lane & 15;         // dest chunk slot 0..15

    if (tid < 64) { s_sum[tid] = 0.f; s_ssq[tid] = 0.f; }

    floatx4 acc[2];
    acc[0] = (floatx4){0.f, 0.f, 0.f, 0.f};
    acc[1] = (floatx4){0.f, 0.f, 0.f, 0.f};

    // stage one 64-K tile (A: 32 rows, B: 64 rows); 6 asyncs per thread
    auto stage = [&](float* AsB, float* BsB, int kt) {
        #pragma unroll
        for (int j = 0; j < 2; ++j) {
            int g = wave * 2 + j;            // 0..7
            int r = g * 4 + g_r;             // 0..31
            int csrc = g_sl ^ (r & 7);
            async_copy_16(X + (size_t)(row0 + r) * PD + kt + csrc * 4, AsB + g * 256);
        }
        #pragma unroll
        for (int j = 0; j < 4; ++j) {
            int g = wave * 4 + j;            // 0..15
            int r = g * 4 + g_r;             // 0..63
            int csrc = g_sl ^ (r & 7);
            async_copy_16(Wc + (size_t)r * PD + kt + csrc * 4, BsB + g * 256);
        }
    };

    auto compute = [&](const float* AsB, const float* BsB) {
        #pragma unroll
        for (int ks = 0; ks < 2; ++ks) {
            int c0 = ks * 8 + quad * 2;      // first 4-float chunk of my k-octet
            int sw = l16 & 7;
            int rA = wr * 16 + l16;
            floatx4 p0 = *(const floatx4*)&AsB[rA * 64 + ((c0 ^ sw) << 2)];
            floatx4 p1 = *(const floatx4*)&AsB[rA * 64 + (((c0 + 1) ^ sw) << 2)];
            halfx8 af;
            af[0] = (_Float16)p0[0]; af[1] = (_Float16)p0[1];
            af[2] = (_Float16)p0[2]; af[3] = (_Float16)p0[3];
            af[4] = (_Float16)p1[0]; af[5] = (_Float16)p1[1];
            af[6] = (_Float16)p1[2]; af[7] = (_Float16)p1[3];
            #pragma unroll
            for (int ni = 0; ni < 2; ++ni) {
                int rB = wn * 32 + ni * 16 + l16;
                floatx4 q0 = *(const floatx4*)&BsB[rB * 64 + ((c0 ^ sw) << 2)];
                floatx4 q1 = *(const floatx4*)&BsB[rB * 64 + (((c0 + 1) ^ sw) << 2)];
                halfx8 bf;
                bf[0] = (_Float16)q0[0]; bf[1] = (_Float16)q0[1];
                bf[2] = (_Float16)q0[2]; bf[3] = (_Float16)q0[3];
                bf[4] = (_Float16)q1[0]; bf[5] = (_Float16)q1[1];
                bf[6] = (_Float16)q1[2]; bf[7] = (_Float16)q1[3];
                acc[ni] = __builtin_amdgcn_mfma_f32_16x16x32_f16(af, bf, acc[ni], 0, 0, 0);
            }
        }
    };

    // Counted-vmcnt double-buffer pipeline (R2-verified correct).
    stage(As[0], Bs[0], 0);
    #pragma unroll
    for (int t = 0; t < 12; ++t) {
        const int cur = t & 1;
        if (t < 11) {
            stage(As[cur ^ 1], Bs[cur ^ 1], (t + 1) * 64);
            asm volatile("s_waitcnt vmcnt(6)\n\ts_barrier" ::: "memory");
        } else {
            asm volatile("s_waitcnt vmcnt(0)\n\ts_barrier" ::: "memory");
        }
        compute(As[cur], Bs[cur]);
        asm volatile("s_waitcnt lgkmcnt(0)\n\ts_barrier" ::: "memory");
    }

    // epilogue: D col (n) = attr, D row (m) = quad*4 + r (m89-verified layout)
    float keep[2][4];
    int cols[2];
    #pragma unroll
    for (int ni = 0; ni < 2; ++ni) {
        int col = wn * 32 + ni * 16 + l16;
        cols[ni] = col;
        if (col < PA) {
            float bv = bc[col];
            float ps = 0.f, pss = 0.f;
            #pragma unroll
            for (int r = 0; r < 4; ++r) {
                float v = acc[ni][r] + bv;
                keep[ni][r] = v;
                ps += v; pss += v * v;
            }
            atomicAdd(&s_sum[col], ps);
            atomicAdd(&s_ssq[col], pss);
        }
    }
    __syncthreads();
    if (tid < PA) {
        atomicAdd(&stats[tid], s_sum[tid]);        // device-scope RMW (coherent)
        atomicAdd(&stats[64 + tid], s_ssq[tid]);
    }
    __syncthreads();   // drains vmcnt: block's stats atomics complete before arrive

    // ---- spin barrier: all cross-block traffic via device-scope atomics ----
    if (tid == 0) {
        __hip_atomic_fetch_add(counter, 1u, __ATOMIC_ACQ_REL, __HIP_MEMORY_SCOPE_AGENT);
        while (__hip_atomic_load(counter, __ATOMIC_ACQUIRE, __HIP_MEMORY_SCOPE_AGENT) < NBLK)
            __builtin_amdgcn_s_sleep(8);
    }
    __syncthreads();

    // ================= BN finalize from registers =================
    const float invB = 1.0f / (float)PM;
    #pragma unroll
    for (int ni = 0; ni < 2; ++ni) {
        int col = cols[ni];
        if (col < PA) {
            float s  = __hip_atomic_load(&stats[col],      __ATOMIC_RELAXED, __HIP_MEMORY_SCOPE_AGENT);
            float ss = __hip_atomic_load(&stats[64 + col], __ATOMIC_RELAXED, __HIP_MEMORY_SCOPE_AGENT);
            float mean = s * invB;
            float var  = ss * invB - mean * mean;
            float inv  = rsqrtf(var + 1e-5f);
            float scale = gamma[col] * inv;
            float shift = beta[col] - mean * scale;
            int rowb = row0 + wr * 16 + quad * 4;
            #pragma unroll
            for (int r = 0; r < 4; ++r)
                out[(size_t)(rowb + r) * PA + col] = keep[ni][r] * scale + shift;
        }
    }
}

// ------------------- launch -------------------
extern "C" void kernel_launch(void* const* d_in, const int* in_sizes, int n_in,
                              void* d_out, int out_size, void* d_ws, size_t ws_size,
                              hipStream_t stream) {
    const float* x       = (const float*)d_in[0];
    const float* W_embed = (const float*)d_in[1];
    const float* b_embed = (const float*)d_in[2];
    const float* W_attr  = (const float*)d_in[3];
    const float* b_attr  = (const float*)d_in[4];
    const float* gamma   = (const float*)d_in[5];
    const float* beta    = (const float*)d_in[6];
    float* out = (float*)d_out;

    char* ws = (char*)d_ws;
    float* wc32          = (float*)(ws);            // 64*768*4 = 196608
    float* bc            = (float*)(ws + 196608);   // 64*4     = 256
    float* stats         = (float*)(ws + 196864);   // 128*4    = 512
    unsigned int* counter = (unsigned int*)(ws + 197376);

    prep_kernel<<<95, 256, 0, stream>>>(W_embed, b_embed, W_attr, b_attr,
                                        wc32, bc, stats, counter);
    gemm_bn_kernel<<<512, 256, 0, stream>>>(x, wc32, bc, gamma, beta, out,
                                            stats, counter);
}

// Round 4
// 151.500 us; speedup vs baseline: 1.7318x; 1.2350x over previous
//
#include <hip/hip_runtime.h>

// ---- types ----
typedef _Float16 halfx8 __attribute__((ext_vector_type(8)));
typedef float floatx4 __attribute__((ext_vector_type(4)));

#define GLOBAL_AS __attribute__((address_space(1)))
#define LDS_AS __attribute__((address_space(3)))

// async global->LDS, 16B per lane; LDS dest = wave-uniform base + lane*16
__device__ __forceinline__ void async_copy_16(const void* g, void* l) {
    __builtin_amdgcn_global_load_lds((GLOBAL_AS void*)g, (LDS_AS void*)l, 16, 0, 0);
}

// problem dims
#define PM 16384
#define PD 768
#define PA 51
#define NBLK 256u

// Math identity (verified): logits = x @ (Wa@We)^T + (Wa@b_embed + b_attr).

// ================= prep: wc16 (fp16 W_comb) + b_comb + stats/counter zero ====
// Separate launch so wc16/bc cross a kernel boundary (runtime-guaranteed
// coherence). 95 blocks x 4 waves = 380 waves; 377 used.
// wc16 values are bit-identical to the old per-tile fp32->fp16 cvt path.
__global__ __launch_bounds__(256) void prep_kernel(
    const float* __restrict__ We, const float* __restrict__ be,
    const float* __restrict__ Wa, const float* __restrict__ ba,
    _Float16* __restrict__ wc16, float* __restrict__ bc, float* __restrict__ stats,
    unsigned int* __restrict__ counter)
{
    const int wave = threadIdx.x >> 6;
    const int lane = threadIdx.x & 63;
    const int Wu = __builtin_amdgcn_readfirstlane((int)blockIdx.x * 4 + wave);

    if (Wu < 312) {
        // wc[a][d] = sum_k Wa[a][k] * We[k][d]; 2 attrs x 64 cols per wave.
        const int pair = Wu / 12;
        const int dchunk = Wu - pair * 12;
        const int a0 = pair * 2;
        const bool has1 = (a0 + 1 < PA);
        const int d = dchunk * 64 + lane;
        const float* wa0 = Wa + (size_t)a0 * PD;                 // wave-uniform -> s_load
        const float* wa1 = Wa + (size_t)(has1 ? a0 + 1 : a0) * PD;
        float acc0 = 0.f, acc1 = 0.f;
        #pragma unroll 32
        for (int k = 0; k < PD; ++k) {
            float w = We[(size_t)k * PD + d];   // coalesced 256B/wave
            acc0 = fmaf(w, wa0[k], acc0);
            acc1 = fmaf(w, wa1[k], acc1);
        }
        wc16[(size_t)a0 * PD + d] = (_Float16)acc0;
        if (has1) wc16[(size_t)(a0 + 1) * PD + d] = (_Float16)acc1;
    } else if (Wu < 325) {
        // zero pad rows 51..63 so B-staging reads defined data
        const int r = PA + (Wu - 312);
        #pragma unroll
        for (int j = 0; j < 12; ++j)
            wc16[(size_t)r * PD + j * 64 + lane] = (_Float16)0.f;
    } else if (Wu < 376) {
        // bc[a] = dot(Wa[a], b_embed) + b_attr[a]; one wave per attr
        const int a = Wu - 325;
        float p = 0.f;
        #pragma unroll
        for (int j = 0; j < 12; ++j) {
            int k = j * 64 + lane;
            p = fmaf(Wa[(size_t)a * PD + k], be[k], p);
        }
        #pragma unroll
        for (int off = 32; off; off >>= 1) p += __shfl_down(p, off);
        if (lane == 0) bc[a] = p + ba[a];
    } else if (Wu == 376) {
        stats[lane] = 0.f;
        stats[64 + lane] = 0.f;
        if (lane == 0) *counter = 0u;            // reset spin barrier each replay
    }
}

// ================= fused GEMM + BN (regular launch, spin barrier) =============
// 256 blocks x 512 threads = 1 block/CU (LDS 144.5 KB forces it), guaranteed
// co-resident (R3 empirically proved 512 x 2/CU; this is half the pressure).
// B (wc16) staged into LDS ONCE as fp16; A triple-buffered with counted
// vmcnt(4) so tile-t loads are issued 2 iterations before their wait.
__global__ void __launch_bounds__(512, 1) gemm_bn_kernel(
    const float* __restrict__ X,        // [16384][768] fp32
    const _Float16* __restrict__ Wc16,  // [64][768] fp16, rows >= 51 zero
    const float* __restrict__ bc,       // [64]
    const float* __restrict__ gamma,
    const float* __restrict__ beta,
    float* __restrict__ out,            // [16384][51]
    float* __restrict__ stats,          // [0..50]=sum, [64..114]=sumsq
    unsigned int* __restrict__ counter)
{
    __shared__ __attribute__((aligned(16))) float As[3][64 * 64];   // 3 x 16 KB
    __shared__ __attribute__((aligned(16))) _Float16 Bh[64 * PD];   // 96 KB
    __shared__ float s_sum[64];
    __shared__ float s_ssq[64];

    const int tid = threadIdx.x;
    const int wave = tid >> 6;          // 0..7
    const int lane = tid & 63;
    const int quad = lane >> 4;
    const int l16 = lane & 15;
    const int wr = wave & 3;            // row group: rows wr*16..+16
    const int wn = wave >> 2;           // col group: cols wn*32..+32
    const int row0 = (int)blockIdx.x * 64;

    if (tid < 64) { s_sum[tid] = 0.f; s_ssq[tid] = 0.f; }

    // ---- stage B ONCE: 8 waves x 12 issues x 1KB = 96 KB, row-XOR-swizzled ----
    // LDS chunk (16B) gc holds source chunk (gc&~7)|((gc&7)^(row&7)).
    #pragma unroll
    for (int j = 0; j < 12; ++j) {
        int gc = (wave * 12 + j) * 64 + lane;          // global 16B-chunk 0..6143
        int r = gc / 96;                               // attr row (96 chunks/row)
        int c = gc - r * 96;
        int csw = (c & ~7) | ((c & 7) ^ (r & 7));
        async_copy_16(Wc16 + (size_t)r * PD + csw * 8,
                      (char*)Bh + (size_t)(wave * 12 + j) * 1024);
    }
    asm volatile("" ::: "memory");      // keep B issues ordered before A issues

    // ---- A staging: one 64x64 fp32 tile = 16 KB = 2 issues/wave ----
    auto stageA = [&](int buf, int kt) {
        #pragma unroll
        for (int j = 0; j < 2; ++j) {
            int chunkbase = (wave * 2 + j) * 64;       // wave-uniform
            int chunk = chunkbase + lane;              // 0..1023
            int r = chunk >> 4;                        // row 0..63
            int c = chunk & 15;
            int csw = (c & 8) | ((c & 7) ^ (r & 7));
            async_copy_16(X + (size_t)(row0 + r) * PD + kt + csw * 4,
                          (char*)&As[buf][0] + (size_t)chunkbase * 16);
        }
        asm volatile("" ::: "memory");  // preserve issue order (vmcnt counting)
    };

    floatx4 acc[2];
    acc[0] = (floatx4){0.f, 0.f, 0.f, 0.f};
    acc[1] = (floatx4){0.f, 0.f, 0.f, 0.f};

    auto computeT = [&](int t, const float* AsB) {
        #pragma unroll
        for (int ks = 0; ks < 2; ++ks) {
            int c0 = ks * 8 + quad * 2;      // first 4-float chunk of my k-octet
            int sw = l16 & 7;
            int rA = wr * 16 + l16;
            floatx4 p0 = *(const floatx4*)&AsB[rA * 64 + ((c0 ^ sw) << 2)];
            floatx4 p1 = *(const floatx4*)&AsB[rA * 64 + (((c0 + 1) ^ sw) << 2)];
            halfx8 af;
            af[0] = (_Float16)p0[0]; af[1] = (_Float16)p0[1];
            af[2] = (_Float16)p0[2]; af[3] = (_Float16)p0[3];
            af[4] = (_Float16)p1[0]; af[5] = (_Float16)p1[1];
            af[6] = (_Float16)p1[2]; af[7] = (_Float16)p1[3];
            #pragma unroll
            for (int ni = 0; ni < 2; ++ni) {
                int rB = wn * 32 + ni * 16 + l16;
                // global half-chunk = t*8 + ks*4 + quad; XOR low3 with row
                int hc = t * 8 + (((ks * 4 + quad)) ^ (rB & 7));
                halfx8 bf = *(const halfx8*)&Bh[(size_t)rB * PD + (hc << 3)];
                acc[ni] = __builtin_amdgcn_mfma_f32_16x16x32_f16(af, bf, acc[ni], 0, 0, 0);
            }
        }
    };

    // 3-deep counted-vmcnt pipeline. Outstanding at loop top (steady): tiles
    // t,t+1,t+2 = 6 A-loads (+B before t=0). vmcnt(4) -> tile t (and B) done.
    stageA(0, 0);
    stageA(1, 64);
    stageA(2, 128);
    #pragma unroll
    for (int t = 0; t < 12; ++t) {
        if (t <= 9)       asm volatile("s_waitcnt vmcnt(4)\n\ts_barrier" ::: "memory");
        else if (t == 10) asm volatile("s_waitcnt vmcnt(2)\n\ts_barrier" ::: "memory");
        else              asm volatile("s_waitcnt vmcnt(0)\n\ts_barrier" ::: "memory");
        computeT(t, &As[t % 3][0]);
        asm volatile("s_waitcnt lgkmcnt(0)\n\ts_barrier" ::: "memory");
        if (t + 3 < 12) stageA(t % 3, (t + 3) * 64);
    }

    // epilogue: D col (n) = attr, D row (m) = quad*4 + r (m89-verified layout)
    float keep[2][4];
    int cols[2];
    #pragma unroll
    for (int ni = 0; ni < 2; ++ni) {
        int col = wn * 32 + ni * 16 + l16;
        cols[ni] = col;
        if (col < PA) {
            float bv = bc[col];
            float ps = 0.f, pss = 0.f;
            #pragma unroll
            for (int r = 0; r < 4; ++r) {
                float v = acc[ni][r] + bv;
                keep[ni][r] = v;
                ps += v; pss += v * v;
            }
            atomicAdd(&s_sum[col], ps);
            atomicAdd(&s_ssq[col], pss);
        }
    }
    __syncthreads();
    if (tid < PA) {
        atomicAdd(&stats[tid], s_sum[tid]);        // device-scope RMW (coherent)
        atomicAdd(&stats[64 + tid], s_ssq[tid]);
    }
    __syncthreads();   // drains vmcnt: block's stats atomics complete before arrive

    // ---- spin barrier: all cross-block traffic via device-scope atomics ----
    if (tid == 0) {
        __hip_atomic_fetch_add(counter, 1u, __ATOMIC_ACQ_REL, __HIP_MEMORY_SCOPE_AGENT);
        while (__hip_atomic_load(counter, __ATOMIC_ACQUIRE, __HIP_MEMORY_SCOPE_AGENT) < NBLK)
            __builtin_amdgcn_s_sleep(8);
    }
    __syncthreads();

    // ================= BN finalize from registers =================
    const float invB = 1.0f / (float)PM;
    #pragma unroll
    for (int ni = 0; ni < 2; ++ni) {
        int col = cols[ni];
        if (col < PA) {
            float s  = __hip_atomic_load(&stats[col],      __ATOMIC_RELAXED, __HIP_MEMORY_SCOPE_AGENT);
            float ss = __hip_atomic_load(&stats[64 + col], __ATOMIC_RELAXED, __HIP_MEMORY_SCOPE_AGENT);
            float mean = s * invB;
            float var  = ss * invB - mean * mean;
            float inv  = rsqrtf(var + 1e-5f);
            float scale = gamma[col] * inv;
            float shift = beta[col] - mean * scale;
            int rowb = row0 + wr * 16 + quad * 4;
            #pragma unroll
            for (int r = 0; r < 4; ++r)
                out[(size_t)(rowb + r) * PA + col] = keep[ni][r] * scale + shift;
        }
    }
}

// ------------------- launch -------------------
extern "C" void kernel_launch(void* const* d_in, const int* in_sizes, int n_in,
                              void* d_out, int out_size, void* d_ws, size_t ws_size,
                              hipStream_t stream) {
    const float* x       = (const float*)d_in[0];
    const float* W_embed = (const float*)d_in[1];
    const float* b_embed = (const float*)d_in[2];
    const float* W_attr  = (const float*)d_in[3];
    const float* b_attr  = (const float*)d_in[4];
    const float* gamma   = (const float*)d_in[5];
    const float* beta    = (const float*)d_in[6];
    float* out = (float*)d_out;

    char* ws = (char*)d_ws;
    _Float16* wc16        = (_Float16*)(ws);          // 64*768*2 = 98304
    float* bc             = (float*)(ws + 98304);     // 64*4     = 256
    float* stats          = (float*)(ws + 98816);     // 128*4    = 512
    unsigned int* counter = (unsigned int*)(ws + 99584);

    prep_kernel<<<95, 256, 0, stream>>>(W_embed, b_embed, W_attr, b_attr,
                                        wc16, bc, stats, counter);
    gemm_bn_kernel<<<256, 512, 0, stream>>>(x, wc16, bc, gamma, beta, out,
                                            stats, counter);
}

// Round 5
// 147.106 us; speedup vs baseline: 1.7835x; 1.0299x over previous
//
#include <hip/hip_runtime.h>

// ---- types ----
typedef _Float16 halfx8 __attribute__((ext_vector_type(8)));
typedef float floatx4 __attribute__((ext_vector_type(4)));

#define GLOBAL_AS __attribute__((address_space(1)))
#define LDS_AS __attribute__((address_space(3)))

// async global->LDS, 16B per lane; LDS dest = wave-uniform base + lane*16
__device__ __forceinline__ void async_copy_16(const void* g, void* l) {
    __builtin_amdgcn_global_load_lds((GLOBAL_AS void*)g, (LDS_AS void*)l, 16, 0, 0);
}

// problem dims
#define PM 16384
#define PD 768
#define PA 51
#define NBLK 256u

// Math identity (verified): logits = x @ (Wa@We)^T + (Wa@b_embed + b_attr).

// Pre-fragmented B layout: frag(ks,n) = 1KB block at half-index (ks*4+n)*512;
// lane L, elem j holds Wc[n*16 + (L&15)][ks*32 + (L>>4)*8 + j].
// Inverse for writer: given (a,d):
__device__ __forceinline__ size_t fragidx(int a, int d) {
    return (size_t)(d >> 5) * 2048 + (size_t)(a >> 4) * 512
         + (size_t)((a & 15) | (((d >> 3) & 3) << 4)) * 8 + (d & 7);
}

// ================= prep: fragmented W_comb + b_comb + stats/counter zero =====
// Separate launch so wfrag/bc cross a kernel boundary (runtime coherence).
// 95 blocks x 4 waves = 380 waves; 377 used.
__global__ __launch_bounds__(256) void prep_kernel(
    const float* __restrict__ We, const float* __restrict__ be,
    const float* __restrict__ Wa, const float* __restrict__ ba,
    _Float16* __restrict__ wfrag, float* __restrict__ bc, float* __restrict__ stats,
    unsigned int* __restrict__ counter)
{
    const int wave = threadIdx.x >> 6;
    const int lane = threadIdx.x & 63;
    const int Wu = __builtin_amdgcn_readfirstlane((int)blockIdx.x * 4 + wave);

    if (Wu < 312) {
        // wc[a][d] = sum_k Wa[a][k] * We[k][d]; 2 attrs x 64 cols per wave.
        const int pair = Wu / 12;
        const int dchunk = Wu - pair * 12;
        const int a0 = pair * 2;
        const bool has1 = (a0 + 1 < PA);
        const int d = dchunk * 64 + lane;
        const float* wa0 = Wa + (size_t)a0 * PD;                 // wave-uniform -> s_load
        const float* wa1 = Wa + (size_t)(has1 ? a0 + 1 : a0) * PD;
        float acc0 = 0.f, acc1 = 0.f;
        #pragma unroll 32
        for (int k = 0; k < PD; ++k) {
            float w = We[(size_t)k * PD + d];   // coalesced 256B/wave
            acc0 = fmaf(w, wa0[k], acc0);
            acc1 = fmaf(w, wa1[k], acc1);
        }
        wfrag[fragidx(a0, d)] = (_Float16)acc0;
        if (has1) wfrag[fragidx(a0 + 1, d)] = (_Float16)acc1;
    } else if (Wu < 325) {
        // zero pad rows 51..63 so B reads defined data
        const int r = PA + (Wu - 312);
        #pragma unroll
        for (int j = 0; j < 12; ++j)
            wfrag[fragidx(r, j * 64 + lane)] = (_Float16)0.f;
    } else if (Wu < 376) {
        // bc[a] = dot(Wa[a], b_embed) + b_attr[a]; one wave per attr
        const int a = Wu - 325;
        float p = 0.f;
        #pragma unroll
        for (int j = 0; j < 12; ++j) {
            int k = j * 64 + lane;
            p = fmaf(Wa[(size_t)a * PD + k], be[k], p);
        }
        #pragma unroll
        for (int off = 32; off; off >>= 1) p += __shfl_down(p, off);
        if (lane == 0) bc[a] = p + ba[a];
    } else if (Wu == 376) {
        stats[lane] = 0.f;
        stats[64 + lane] = 0.f;
        if (lane == 0) *counter = 0u;            // reset spin barrier each replay
    }
}

// ================= fused GEMM + BN: barrier-free K-loop ======================
// 256 blocks x 256 thr (4 waves, 1 block/CU by LDS). Each wave independently
// computes 16 rows x 64 attrs. B staged once (one barrier), then the K-loop
// has NO block barriers: per-wave private triple-buffered A via global_load_lds
// + per-wave counted vmcnt. The only vmem ops in the loop are the counted DMAs.
__global__ void __launch_bounds__(256, 1) gemm_bn_kernel(
    const float* __restrict__ X,        // [16384][768] fp32
    const _Float16* __restrict__ Wfrag, // 96KB pre-fragmented
    const float* __restrict__ bc,       // [64]
    const float* __restrict__ gamma,
    const float* __restrict__ beta,
    float* __restrict__ out,            // [16384][51]
    float* __restrict__ stats,          // [0..50]=sum, [64..114]=sumsq
    unsigned int* __restrict__ counter)
{
    __shared__ __attribute__((aligned(16))) _Float16 Bh[24 * 4 * 512]; // 96 KB
    __shared__ __attribute__((aligned(16))) float Atile[4][3][16 * 64]; // 48 KB
    __shared__ float s_sum[64];
    __shared__ float s_ssq[64];

    const int tid = threadIdx.x;
    const int wave = tid >> 6;          // 0..3
    const int lane = tid & 63;
    const int quad = lane >> 4;
    const int l16 = lane & 15;
    const int m0 = (int)blockIdx.x * 64 + wave * 16;   // my 16 rows

    if (tid < 64) { s_sum[tid] = 0.f; s_ssq[tid] = 0.f; }

    // ---- stage B once: 96 x 1KB chunks, 24 per wave, lane-linear ----
    #pragma unroll
    for (int j = 0; j < 24; ++j) {
        int ch = wave * 24 + j;                        // 0..95
        async_copy_16((const char*)Wfrag + (size_t)ch * 1024 + (size_t)lane * 16,
                      (char*)Bh + (size_t)ch * 1024);
    }
    asm volatile("" ::: "memory");

    // ---- A staging: 16 rows x 64 cols fp32 = 4 KB = 4 issues, XOR swizzle ----
    auto stageA = [&](int buf, int kt) {
        #pragma unroll
        for (int j = 0; j < 4; ++j) {
            int r = j * 4 + (lane >> 4);               // 0..15
            int c = lane & 15;
            int csw = (c & 8) | ((c & 7) ^ (r & 7));
            async_copy_16(X + (size_t)(m0 + r) * PD + kt + csw * 4,
                          (char*)&Atile[wave][buf][0] + (size_t)(j * 64) * 16);
        }
        asm volatile("" ::: "memory");
    };

    floatx4 acc[4];
    #pragma unroll
    for (int n = 0; n < 4; ++n) acc[n] = (floatx4){0.f, 0.f, 0.f, 0.f};

    // prologue: 3-deep A prefetch; barrier only for B visibility
    stageA(0, 0);
    stageA(1, 64);
    stageA(2, 128);
    asm volatile("s_waitcnt vmcnt(12)\n\ts_barrier" ::: "memory"); // B done, A in flight

    // ---- barrier-free K-loop: 12 macro-steps x 2 k-steps ----
    #pragma unroll
    for (int mm = 0; mm < 12; ++mm) {
        if (mm <= 9)       asm volatile("s_waitcnt vmcnt(8)" ::: "memory");
        else if (mm == 10) asm volatile("s_waitcnt vmcnt(4)" ::: "memory");
        else               asm volatile("s_waitcnt vmcnt(0)" ::: "memory");
        const float* At = &Atile[wave][mm % 3][0];
        #pragma unroll
        for (int km = 0; km < 2; ++km) {
            const int ks = mm * 2 + km;
            // A-frag: row l16, k-chunks cc, cc+1 (R4-verified mapping)
            int cc = km * 8 + quad * 2;
            int s3 = l16 & 7;
            floatx4 p0 = *(const floatx4*)&At[l16 * 64 + (((cc & 8) | ((cc & 7) ^ s3)) << 2)];
            floatx4 p1 = *(const floatx4*)&At[l16 * 64 + ((((cc + 1) & 8) | (((cc + 1) & 7) ^ s3)) << 2)];
            halfx8 af;
            af[0] = (_Float16)p0[0]; af[1] = (_Float16)p0[1];
            af[2] = (_Float16)p0[2]; af[3] = (_Float16)p0[3];
            af[4] = (_Float16)p1[0]; af[5] = (_Float16)p1[1];
            af[6] = (_Float16)p1[2]; af[7] = (_Float16)p1[3];
            #pragma unroll
            for (int n = 0; n < 4; ++n) {
                halfx8 bf = *(const halfx8*)&Bh[(size_t)(ks * 4 + n) * 512 + (size_t)lane * 8];
                acc[n] = __builtin_amdgcn_mfma_f32_16x16x32_f16(af, bf, acc[n], 0, 0, 0);
            }
        }
        if (mm + 3 < 12) stageA(mm % 3, (mm + 3) * 64);
    }

    // epilogue: D col = n*16 + (lane&15), row = m0 + quad*4 + r (verified layout)
    float keep[4][4];
    #pragma unroll
    for (int n = 0; n < 4; ++n) {
        int col = n * 16 + l16;
        if (col < PA) {
            float bv = bc[col];
            float ps = 0.f, pss = 0.f;
            #pragma unroll
            for (int r = 0; r < 4; ++r) {
                float v = acc[n][r] + bv;
                keep[n][r] = v;
                ps += v; pss += v * v;
            }
            atomicAdd(&s_sum[col], ps);
            atomicAdd(&s_ssq[col], pss);
        }
    }
    __syncthreads();
    if (tid < PA) {
        atomicAdd(&stats[tid], s_sum[tid]);        // device-scope RMW (coherent)
        atomicAdd(&stats[64 + tid], s_ssq[tid]);
    }
    __syncthreads();   // block's stats atomics issued+drained before arrive

    // ---- spin barrier: relaxed polls (no per-poll invalidate), one acquire ----
    if (tid == 0) {
        __hip_atomic_fetch_add(counter, 1u, __ATOMIC_ACQ_REL, __HIP_MEMORY_SCOPE_AGENT);
        while (__hip_atomic_load(counter, __ATOMIC_RELAXED, __HIP_MEMORY_SCOPE_AGENT) < NBLK)
            __builtin_amdgcn_s_sleep(8);
        (void)__hip_atomic_load(counter, __ATOMIC_ACQUIRE, __HIP_MEMORY_SCOPE_AGENT);
    }
    __syncthreads();

    // ================= BN finalize from registers =================
    const float invB = 1.0f / (float)PM;
    #pragma unroll
    for (int n = 0; n < 4; ++n) {
        int col = n * 16 + l16;
        if (col < PA) {
            float s  = __hip_atomic_load(&stats[col],      __ATOMIC_RELAXED, __HIP_MEMORY_SCOPE_AGENT);
            float ss = __hip_atomic_load(&stats[64 + col], __ATOMIC_RELAXED, __HIP_MEMORY_SCOPE_AGENT);
            float mean = s * invB;
            float var  = ss * invB - mean * mean;
            float inv  = rsqrtf(var + 1e-5f);
            float scale = gamma[col] * inv;
            float shift = beta[col] - mean * scale;
            int rowb = m0 + quad * 4;
            #pragma unroll
            for (int r = 0; r < 4; ++r)
                out[(size_t)(rowb + r) * PA + col] = keep[n][r] * scale + shift;
        }
    }
}

// ------------------- launch -------------------
extern "C" void kernel_launch(void* const* d_in, const int* in_sizes, int n_in,
                              void* d_out, int out_size, void* d_ws, size_t ws_size,
                              hipStream_t stream) {
    const float* x       = (const float*)d_in[0];
    const float* W_embed = (const float*)d_in[1];
    const float* b_embed = (const float*)d_in[2];
    const float* W_attr  = (const float*)d_in[3];
    const float* b_attr  = (const float*)d_in[4];
    const float* gamma   = (const float*)d_in[5];
    const float* beta    = (const float*)d_in[6];
    float* out = (float*)d_out;

    char* ws = (char*)d_ws;
    _Float16* wfrag       = (_Float16*)(ws);          // 24*4*512*2 = 98304
    float* bc             = (float*)(ws + 98304);     // 64*4
    float* stats          = (float*)(ws + 98816);     // 128*4
    unsigned int* counter = (unsigned int*)(ws + 99584);

    prep_kernel<<<95, 256, 0, stream>>>(W_embed, b_embed, W_attr, b_attr,
                                        wfrag, bc, stats, counter);
    gemm_bn_kernel<<<256, 256, 0, stream>>>(x, wfrag, bc, gamma, beta, out,
                                            stats, counter);
}